// Round 15
// baseline (9141.443 us; speedup 1.0000x reference)
//
#include <hip/hip_runtime.h>
#include <math.h>

using ushort_t = unsigned short;
using short8 = __attribute__((ext_vector_type(8))) short;
using floatx16 = __attribute__((ext_vector_type(16))) float;
using int4v = __attribute__((ext_vector_type(4))) int;
using int2v = __attribute__((ext_vector_type(2))) int;

constexpr int kB = 512, kT = 256, kH = 512, kHor = 64;
constexpr int NG = 4 * kH;  // 2048 packed gate rows
constexpr int HSP = 36;     // epilogue h-staging row pitch (ushorts, 32+4 pad)

__device__ __forceinline__ ushort_t f2bf(float v) {
  unsigned u = __builtin_bit_cast(unsigned, v);
  return (ushort_t)((u + 0x7FFFu + ((u >> 16) & 1u)) >> 16);
}
__device__ __forceinline__ float bf2f(ushort_t b) {
  unsigned u = (unsigned)b << 16;
  return __builtin_bit_cast(float, u);
}
__device__ __forceinline__ float sig_(float x) { return 1.0f / (1.0f + __expf(-x)); }

__device__ __forceinline__ void async16(const ushort_t* g, ushort_t* l) {
  __builtin_amdgcn_global_load_lds(
      (const __attribute__((address_space(1))) void*)g,
      (__attribute__((address_space(3))) void*)l, 16, 0, 0);
}

struct UnitP {
  const ushort_t *Whi, *Wlo;            // packed weights [r=j*4+g][k], stride Kw
  const ushort_t *B0hi, *B0lo;          // h source planes (B,H), k 0..511
  const ushort_t *B1hi, *B1lo;          // k 512..1023 (unit B)
  const float* bias;                    // packed [j*4+g]
  ushort_t *Hhi, *Hlo;                  // output h planes (B,H)
  int Kw;                               // 512 or 1024
};

struct EX {
  const float* xsrc; const float* wx; int xmode; int tcol;  // unit-A input term
  float* outp; int ocol;                // ocol>=0: out[:,ocol] = xsrc (LLC)
  float* inp_next; const float* headb; int do_init;
  const float* headW; float* head_acc; int do_head;
};

struct Ptrs {
  const float* x;
  const ushort_t *w0eh, *w0el, *w1eh, *w1el;
  const ushort_t *w0dh, *w0dl, *w1dh, *w1dl;
  ushort_t *h0h[2], *h0l[2], *h1h[2], *h1l[2];
  const float *be0, *be1, *bd0, *bd1, *wxe, *wxd;
  float *ib0, *ib1;
  const float *hW, *hb;
  float* out;
  unsigned *bar1, *barR, *barG;
};

// GEMM phase: BM=128 gate-rows x BN=64 batch, BK=32. 512 threads, 8 waves,
// each wave one 32x32 tile (wm = wv&3 m-tile, wn = wv>>2 n-tile).
// Rationale (r14 counters): phase time == sc h-read stream (96 MB/phase @
// ~5.6 TB/s MALL). h-stream is proportional to 1/BM (mb-blocks re-reading the
// same h panel); weight stream is prop. to 1/BN. BM 64->128 with BN fixed
// halves sc bytes (96->48 MB/phase) at UNCHANGED weight bytes and unchanged
// 3 MB/XCD L2 weight footprint (r10's failure was shrinking BN).
// A (weights): global_load_lds DMA, double-buffered. Waves 0..3 each stage
//   4 KB/step (wave<2: hi plane, else lo; rows (wv&1)*64 + [0,64)).
// B (h planes): sc0 sc1 LLC-coherent reg staging, waves 4 (hi) / 5 (lo),
//   4 static dwordx4 each, double-buffered, 1-step prefetch (r14 cadence).
// Waves 6,7: compute-only (hit the same barriers).
// LDS (ushorts): Abuf0 [0,8192) (hi 4096|lo 4096), Abuf1 [8192,16384),
//   Bbuf0 [16384,20480) (hi 2048|lo 2048), Bbuf1 [20480,24576). 48 KB.
// Slot layout per plane (16B slots): q = row*4 + (k8 ^ (row&3)).
// Global k-order and per-k8 MFMA triple identical to r14 -> bitwise-same acc.
__device__ __forceinline__ void run_unit(const UnitP& U, const EX& E, const bool isB,
                                         const int mb, const int nb,
                                         ushort_t* sm, ushort_t* hshi, ushort_t* hslo,
                                         float* creg) {
  const int tid = threadIdx.x;          // 0..511
  const int m0blk = mb * 128;
  const int n0blk = nb * 64;
  const int nkt = U.Kw >> 5;            // 16 or 32

  const int wv = tid >> 6;              // 0..7
  const int ln = tid & 63;
  const int l31 = ln & 31;
  const int half = ln >> 5;
  const int wm = wv & 3;                // m-tile 0..3
  const int wn = wv >> 2;               // n-tile 0..1
  const int m0w = wm * 32, n0w = wn * 32;

  const bool stA = wv < 4;
  const bool stB = (wv == 4) || (wv == 5);

  // lane decomposition for staging: r4 = ln>>2 (16 rows/issue), sl = ln&3
  const int r4 = ln >> 2;
  const int sl = ln & 3;
  const int k8s = sl ^ (r4 & 3);        // source k8 for swizzled slot

  // ---- A staging (waves 0..3) ----
  const ushort_t* gsrcA = (wv < 2) ? U.Whi : U.Wlo;
  const int rowBase = (wv & 1) * 64;
  const size_t aRowOff = (size_t)(m0blk + rowBase + r4) * U.Kw + k8s * 8;
  const int aLds = ((wv < 2) ? 0 : 4096) + rowBase * 32;  // + bufsel*8192

  auto issueA = [&](int kt, int bufsel) {
    ushort_t* lb = sm + bufsel * 8192 + aLds;
    const ushort_t* g0 = gsrcA + aRowOff + kt * 32;
    #pragma unroll
    for (int i = 0; i < 4; ++i)
      async16(g0 + (size_t)i * 16 * U.Kw, lb + i * 512);
  };

  // ---- B staging (waves 4 hi / 5 lo), 4 static dwordx4 ----
  const ushort_t* b0p = (wv == 4) ? U.B0hi : U.B0lo;
  const ushort_t* b1p = (wv == 4) ? U.B1hi : U.B1lo;
  const int bPl = (wv == 4) ? 0 : 2048;           // plane offset in B buffer
  const size_t bRowOff = (size_t)(n0blk + r4) * kH + k8s * 8;

  int4v q0, q1, q2, q3;
  auto issueB = [&](int ktc) {
    const ushort_t* bsrc = (ktc < 16) ? b0p : b1p;
    const int col0 = (ktc & 15) * 32;
    const ushort_t* g0 = bsrc + bRowOff + col0;
    asm volatile("global_load_dwordx4 %0, %1, off sc0 sc1"
                 : "=v"(q0) : "v"(g0) : "memory");
    asm volatile("global_load_dwordx4 %0, %1, off sc0 sc1"
                 : "=v"(q1) : "v"(g0 + (size_t)16 * kH) : "memory");
    asm volatile("global_load_dwordx4 %0, %1, off sc0 sc1"
                 : "=v"(q2) : "v"(g0 + (size_t)32 * kH) : "memory");
    asm volatile("global_load_dwordx4 %0, %1, off sc0 sc1"
                 : "=v"(q3) : "v"(g0 + (size_t)48 * kH) : "memory");
  };
  auto writeB = [&](int bufsel) {
    ushort_t* b = sm + 16384 + bufsel * 4096 + bPl;
    asm volatile("s_waitcnt vmcnt(0)" ::: "memory");   // q0..q3 materialized
    *(int4v*)(b + ln * 8) = q0;
    *(int4v*)(b + 512 + ln * 8) = q1;
    *(int4v*)(b + 1024 + ln * 8) = q2;
    *(int4v*)(b + 1536 + ln * 8) = q3;
    asm volatile("s_waitcnt lgkmcnt(0)" ::: "memory"); // regs reusable+visible
  };

  floatx16 acc;
  #pragma unroll
  for (int i = 0; i < 16; ++i) acc[i] = 0.0f;

  auto compute = [&](int bufsel) {
    const ushort_t* ba = sm + bufsel * 8192;
    const ushort_t* bb = sm + 16384 + bufsel * 4096;
    #pragma unroll
    for (int ks = 0; ks < 2; ++ks) {
      const int k8 = ks * 2 + half;
      const int ra = m0w + l31;
      const int rb = n0w + l31;
      const int qa = ra * 4 + (k8 ^ (ra & 3));
      const int qb = rb * 4 + (k8 ^ (rb & 3));
      short8 ahi = *(const short8*)(ba + qa * 8);
      short8 alo = *(const short8*)(ba + 4096 + qa * 8);
      short8 bhi = *(const short8*)(bb + qb * 8);
      short8 blo = *(const short8*)(bb + 2048 + qb * 8);
      acc = __builtin_amdgcn_mfma_f32_32x32x16_bf16(alo, bhi, acc, 0, 0, 0);
      acc = __builtin_amdgcn_mfma_f32_32x32x16_bf16(ahi, blo, acc, 0, 0, 0);
      acc = __builtin_amdgcn_mfma_f32_32x32x16_bf16(ahi, bhi, acc, 0, 0, 0);
    }
  };

  // ---- prologue ----
  if (stA) issueA(0, 0);
  if (stB) issueB(0);

  // ---- main loop: 2 barriers per k-step (r14 cadence) ----
  for (int kt = 0; kt < nkt; ++kt) {
    if (kt > 0) {                       // WAR: all done computing buf[(kt+1)&1]
      asm volatile("" ::: "memory");
      __builtin_amdgcn_s_barrier();
      asm volatile("" ::: "memory");
    }
    if (stA) {
      if (kt + 1 < nkt) {
        issueA(kt + 1, (kt + 1) & 1);
        asm volatile("s_waitcnt vmcnt(4)" ::: "memory");  // A(kt) landed
      } else {
        asm volatile("s_waitcnt vmcnt(0)" ::: "memory");
      }
    } else if (stB) {
      writeB(kt & 1);                   // vmcnt(0) inside: B(kt) landed
      if (kt + 1 < nkt) issueB(kt + 1);
    }
    asm volatile("" ::: "memory");
    __builtin_amdgcn_s_barrier();       // buf[kt&1] fully staged & visible
    asm volatile("" ::: "memory");
    compute(kt & 1);
  }
  asm volatile("s_waitcnt vmcnt(0)" ::: "memory");      // nothing dangling

  // ---- epilogue: lane n = n0blk + n0w + l31; 4 j-groups x 4 gates ----
  const int jt0 = mb * 32;
  const int ng = n0blk + n0w + l31;
  float xv = 0.0f;
  if (!isB) {
    if (E.xmode == 0) xv = E.xsrc[(size_t)ng * kT + E.tcol];
    else xv = __hip_atomic_load((float*)&E.xsrc[ng], __ATOMIC_RELAXED,
                                __HIP_MEMORY_SCOPE_AGENT);
  }

  #pragma unroll
  for (int rg = 0; rg < 4; ++rg) {
    const int jl = wm * 8 + rg * 2 + half;      // j within block's 32
    const int jg = jt0 + jl;
    const float4 bi = *(const float4*)&U.bias[jg * 4];
    float gi = acc[rg * 4 + 0] + bi.x;
    float gf = acc[rg * 4 + 1] + bi.y;
    float gg = acc[rg * 4 + 2] + bi.z;
    float go = acc[rg * 4 + 3] + bi.w;
    if (!isB) {
      const float4 wx4 = *(const float4*)&E.wx[jg * 4];
      gi += xv * wx4.x; gf += xv * wx4.y; gg += xv * wx4.z; go += xv * wx4.w;
    }
    const float i_ = sig_(gi), f_ = sig_(gf), g_ = tanhf(gg), o_ = sig_(go);
    const float cn = f_ * creg[rg] + i_ * g_;   // c lives in registers
    creg[rg] = cn;
    const float hn = o_ * tanhf(cn);
    const ushort_t hhi = f2bf(hn);
    const ushort_t hlo = f2bf(hn - bf2f(hhi));
    const int nbk = n0w + l31;
    hshi[nbk * HSP + jl] = hhi;
    hslo[nbk * HSP + jl] = hlo;
  }
  __syncthreads();

  // coalesced h-plane write (B,H): 8 threads/row x 8B/plane, through to LLC
  {
    const int nr = tid >> 3;            // 0..63
    const int jq = (tid & 7) * 4;       // 0..28
    const unsigned a0 = hshi[nr * HSP + jq + 0], a1 = hshi[nr * HSP + jq + 1];
    const unsigned a2 = hshi[nr * HSP + jq + 2], a3 = hshi[nr * HSP + jq + 3];
    const unsigned b0 = hslo[nr * HSP + jq + 0], b1 = hslo[nr * HSP + jq + 1];
    const unsigned b2 = hslo[nr * HSP + jq + 2], b3 = hslo[nr * HSP + jq + 3];
    int2v vh, vl;
    vh[0] = (int)(a0 | (a1 << 16)); vh[1] = (int)(a2 | (a3 << 16));
    vl[0] = (int)(b0 | (b1 << 16)); vl[1] = (int)(b2 | (b3 << 16));
    ushort_t* ph = &U.Hhi[(size_t)(n0blk + nr) * kH + jt0 + jq];
    ushort_t* pl = &U.Hlo[(size_t)(n0blk + nr) * kH + jt0 + jq];
    asm volatile("global_store_dwordx2 %0, %1, off sc0 sc1"
                 :: "v"(ph), "v"(vh) : "memory");
    asm volatile("global_store_dwordx2 %0, %1, off sc0 sc1"
                 :: "v"(pl), "v"(vl) : "memory");
  }

  if (isB) {
    if (E.do_head && tid < 64) {
      float s = 0.0f;
      #pragma unroll
      for (int jb = 0; jb < 32; ++jb)
        s += (bf2f(hshi[tid * HSP + jb]) + bf2f(hslo[tid * HSP + jb])) * E.headW[jt0 + jb];
      atomicAdd(&E.head_acc[n0blk + tid], s);   // device scope -> LLC
    }
  } else if (mb == 0 && tid < 64) {
    const int n = n0blk + tid;
    if (E.do_init)
      __hip_atomic_store(&E.inp_next[n], E.headb[0], __ATOMIC_RELAXED,
                         __HIP_MEMORY_SCOPE_AGENT);
    if (E.ocol >= 0) {
      const float v = __hip_atomic_load((float*)&E.xsrc[n], __ATOMIC_RELAXED,
                                        __HIP_MEMORY_SCOPE_AGENT);
      E.outp[(size_t)n * kHor + E.ocol] = v;
    }
  }
}

// Persistent kernel: 256 blocks x 512 threads (A-team 0..127, B 128..255).
// 2-D XCD map: x = bid&7, kq = bid>>3 (0..15);
//   mb = (kq&3) + 4*(x&3) (16 values, 4/XCD -> enc weights 3 MB, L2-resident)
//   nb = (kq>>2) + 4*(x>>2) (8 values, 4/XCD -> minimal h import)
// A-block bid and B-block bid+128 land on the same XCD (round-robin).
// Per-nb-group barriers (r14 champion): group = 16 A + 16 B = 32 blocks;
// dependency graph is closed within the group (h panel rows, ib, head, out).
__global__ __launch_bounds__(512, 2) void lstm_persist(Ptrs P) {
  __shared__ __align__(16) ushort_t sm[24576];   // A 2x16KB + B 2x8KB = 48KB
  __shared__ __align__(16) ushort_t hshi[64 * HSP];
  __shared__ __align__(16) ushort_t hslo[64 * HSP];

  const int tid = threadIdx.x;
  const int bx = blockIdx.x;
  const bool isB = bx >= 128;
  const int bid = isB ? bx - 128 : bx;
  const int xs = bid & 7;            // ~XCD id under round-robin dispatch
  const int kq = bid >> 3;           // 0..15
  const int mb = (kq & 3) + 4 * (xs & 3);      // 0..15
  const int nb = (kq >> 2) + 4 * (xs >> 2);    // 0..7
  const int grp = nb;                // barrier group: 32 blocks (16 A + 16 B)

  float creg[4] = {0.0f, 0.0f, 0.0f, 0.0f};  // block-private cell state

  int gen = 0;
  auto gbar = [&]() {
    asm volatile("s_waitcnt vmcnt(0)" ::: "memory");  // drain sc-stores
    __syncthreads();
    if (tid == 0) {
      unsigned old = __hip_atomic_fetch_add(&P.bar1[grp * 32], 1u,
                         __ATOMIC_RELAXED, __HIP_MEMORY_SCOPE_AGENT);
      if (old == (unsigned)(gen * 32 + 31))            // last of the 32
        __hip_atomic_store(&P.barG[grp * 32], (unsigned)(gen + 1),
                           __ATOMIC_RELAXED, __HIP_MEMORY_SCOPE_AGENT);
      while (__hip_atomic_load(&P.barG[grp * 32], __ATOMIC_RELAXED,
                               __HIP_MEMORY_SCOPE_AGENT) <= (unsigned)gen)
        __builtin_amdgcn_s_sleep(2);
    }
    __syncthreads();
    ++gen;
  };

  // ---------- encoder: wavefront phases p=0..256 (L0[p] || L1[p-1]) ----------
  for (int p = 0; p <= kT; ++p) {
    const int rd = p & 1, wr = (p + 1) & 1;
    const bool active = isB ? (p >= 1) : (p < kT);
    if (active) {
      UnitP U; EX E = {};
      if (!isB) {
        U = UnitP{P.w0eh, P.w0el, P.h0h[rd], P.h0l[rd], P.h0h[rd], P.h0l[rd],
                  P.be0, P.h0h[wr], P.h0l[wr], 512};
        E.xsrc = P.x; E.wx = P.wxe; E.xmode = 0; E.tcol = p; E.ocol = -1;
      } else {
        U = UnitP{P.w1eh, P.w1el, P.h0h[rd], P.h0l[rd], P.h1h[rd], P.h1l[rd],
                  P.be1, P.h1h[wr], P.h1l[wr], 1024};
        E.ocol = -1;
      }
      run_unit(U, E, isB, mb, nb, sm, hshi, hslo, creg);
    }
    gbar();
  }
  // h0 final in planes[0], h1 final in planes[1]

  // ---------- decoder: serial, 2 phases/step ----------
  for (int t = 0; t < kHor; ++t) {
    const int r0 = t & 1, w0i = (t + 1) & 1;
    const int r1 = (t + 1) & 1, w1i = t & 1;
    float* ibr = (t & 1) ? P.ib1 : P.ib0;
    float* ibw = (t & 1) ? P.ib0 : P.ib1;
    if (!isB) {
      UnitP U = {P.w0dh, P.w0dl, P.h0h[r0], P.h0l[r0], P.h0h[r0], P.h0l[r0],
                 P.bd0, P.h0h[w0i], P.h0l[w0i], 512};
      EX E = {};
      E.wx = P.wxd;
      if (t == 0) { E.xsrc = P.x; E.xmode = 0; E.tcol = 255; E.ocol = -1; }
      else        { E.xsrc = ibr; E.xmode = 1; E.ocol = t - 1; E.outp = P.out; }
      E.do_init = 1; E.inp_next = ibw; E.headb = P.hb;
      run_unit(U, E, false, mb, nb, sm, hshi, hslo, creg);
    }
    gbar();
    if (isB) {
      UnitP U = {P.w1dh, P.w1dl, P.h0h[w0i], P.h0l[w0i], P.h1h[r1], P.h1l[r1],
                 P.bd1, P.h1h[w1i], P.h1l[w1i], 1024};
      EX E = {};
      E.ocol = -1;
      E.do_head = 1; E.headW = P.hW; E.head_acc = ibw;
      run_unit(U, E, true, mb, nb, sm, hshi, hslo, creg);
    }
    gbar();
  }

  // last head output: out[:,63] = ib0 (post-gbar, group-fresh)
  if (!isB && mb == 0 && tid < 64) {
    const int n = nb * 64 + tid;
    P.out[(size_t)n * kHor + 63] =
        __hip_atomic_load(P.ib0 + n, __ATOMIC_RELAXED, __HIP_MEMORY_SCOPE_AGENT);
  }
}

// ---- prep kernels ----
__global__ void prep_w(const float* __restrict__ s0, const float* __restrict__ s1,
                       ushort_t* __restrict__ hi, ushort_t* __restrict__ lo, int Kw) {
  const int k = blockIdx.x * 256 + threadIdx.x;
  const int r = blockIdx.y;                 // packed row j*4+g
  const int j = r >> 2, g = r & 3;
  const int srow = g * kH + j;
  const float v = (k < kH) ? s0[(size_t)srow * kH + k]
                           : s1[(size_t)srow * kH + (k - kH)];
  const ushort_t h = f2bf(v);
  const ushort_t l = f2bf(v - bf2f(h));
  hi[(size_t)r * Kw + k] = h;
  lo[(size_t)r * Kw + k] = l;
}

__global__ void prep_vec(const float* __restrict__ src, float* __restrict__ dst) {
  const int t = blockIdx.x * 256 + threadIdx.x;   // 2048
  const int j = t >> 2, g = t & 3;
  dst[t] = src[g * kH + j];
}

__global__ void init_zero(ushort_t* p0, ushort_t* p1, ushort_t* p2, ushort_t* p3,
                          ushort_t* p4, ushort_t* p5, ushort_t* p6, ushort_t* p7) {
  const int i = blockIdx.x * 256 + threadIdx.x;   // 262144
  p0[i] = 0; p1[i] = 0; p2[i] = 0; p3[i] = 0;
  p4[i] = 0; p5[i] = 0; p6[i] = 0; p7[i] = 0;
}

__global__ void init_bar(unsigned* b) {
  const int i = blockIdx.x * 256 + threadIdx.x;
  if (i < 2112) b[i] = 0;
}

extern "C" void kernel_launch(void* const* d_in, const int* in_sizes, int n_in,
                              void* d_out, int out_size, void* d_ws, size_t ws_size,
                              hipStream_t stream) {
  const float* x     = (const float*)d_in[0];
  const float* eWih0 = (const float*)d_in[1];
  const float* eWhh0 = (const float*)d_in[2];
  const float* eb0   = (const float*)d_in[3];
  const float* eWih1 = (const float*)d_in[4];
  const float* eWhh1 = (const float*)d_in[5];
  const float* eb1   = (const float*)d_in[6];
  const float* dWih0 = (const float*)d_in[7];
  const float* dWhh0 = (const float*)d_in[8];
  const float* db0   = (const float*)d_in[9];
  const float* dWih1 = (const float*)d_in[10];
  const float* dWhh1 = (const float*)d_in[11];
  const float* db1   = (const float*)d_in[12];
  const float* hW    = (const float*)d_in[13];
  const float* hb    = (const float*)d_in[14];
  float* out = (float*)d_out;

  char* w = (char*)d_ws;
  size_t off = 0;
  auto aus = [&](size_t n) { ushort_t* p = (ushort_t*)(w + off); off += ((n * 2 + 255) & ~(size_t)255); return p; };
  auto afl = [&](size_t n) { float* p = (float*)(w + off); off += ((n * 4 + 255) & ~(size_t)255); return p; };

  ushort_t* w0e_hi = aus((size_t)NG * 512); ushort_t* w0e_lo = aus((size_t)NG * 512);
  ushort_t* w1e_hi = aus((size_t)NG * 1024); ushort_t* w1e_lo = aus((size_t)NG * 1024);
  ushort_t* w0d_hi = aus((size_t)NG * 512); ushort_t* w0d_lo = aus((size_t)NG * 512);
  ushort_t* w1d_hi = aus((size_t)NG * 1024); ushort_t* w1d_lo = aus((size_t)NG * 1024);
  ushort_t* h0hi[2] = {aus(kB * kH), aus(kB * kH)};
  ushort_t* h0lo[2] = {aus(kB * kH), aus(kB * kH)};
  ushort_t* h1hi[2] = {aus(kB * kH), aus(kB * kH)};
  ushort_t* h1lo[2] = {aus(kB * kH), aus(kB * kH)};
  float* be0 = afl(NG); float* be1 = afl(NG);
  float* bd0 = afl(NG); float* bd1 = afl(NG);
  float* wxe = afl(NG); float* wxd = afl(NG);
  float* ib0 = afl(kB); float* ib1 = afl(kB);
  unsigned* barb = (unsigned*)(w + off); off += ((2112 * 4 + 255) & ~(size_t)255);

  prep_w<<<dim3(2, NG), 256, 0, stream>>>(eWhh0, eWhh0, w0e_hi, w0e_lo, 512);
  prep_w<<<dim3(4, NG), 256, 0, stream>>>(eWih1, eWhh1, w1e_hi, w1e_lo, 1024);
  prep_w<<<dim3(2, NG), 256, 0, stream>>>(dWhh0, dWhh0, w0d_hi, w0d_lo, 512);
  prep_w<<<dim3(4, NG), 256, 0, stream>>>(dWih1, dWhh1, w1d_hi, w1d_lo, 1024);
  prep_vec<<<8, 256, 0, stream>>>(eb0, be0);
  prep_vec<<<8, 256, 0, stream>>>(eb1, be1);
  prep_vec<<<8, 256, 0, stream>>>(db0, bd0);
  prep_vec<<<8, 256, 0, stream>>>(db1, bd1);
  prep_vec<<<8, 256, 0, stream>>>(eWih0, wxe);
  prep_vec<<<8, 256, 0, stream>>>(dWih0, wxd);
  init_zero<<<1024, 256, 0, stream>>>(h0hi[0], h0hi[1], h0lo[0], h0lo[1],
                                      h1hi[0], h1hi[1], h1lo[0], h1lo[1]);
  init_bar<<<9, 256, 0, stream>>>(barb);

  Ptrs P = {};
  P.x = x;
  P.w0eh = w0e_hi; P.w0el = w0e_lo; P.w1eh = w1e_hi; P.w1el = w1e_lo;
  P.w0dh = w0d_hi; P.w0dl = w0d_lo; P.w1dh = w1d_hi; P.w1dl = w1d_lo;
  P.h0h[0] = h0hi[0]; P.h0h[1] = h0hi[1];
  P.h0l[0] = h0lo[0]; P.h0l[1] = h0lo[1];
  P.h1h[0] = h1hi[0]; P.h1h[1] = h1hi[1];
  P.h1l[0] = h1lo[0]; P.h1l[1] = h1lo[1];
  P.be0 = be0; P.be1 = be1; P.bd0 = bd0; P.bd1 = bd1;
  P.wxe = wxe; P.wxd = wxd;
  P.ib0 = ib0; P.ib1 = ib1;
  P.hW = hW; P.hb = hb;
  P.out = out;
  P.bar1 = barb; P.barR = barb + 2048; P.barG = barb + 1024;

  lstm_persist<<<256, 512, 0, stream>>>(P);
}

// Round 16
// 8689.157 us; speedup vs baseline: 1.0521x; 1.0521x over previous
//
#include <hip/hip_runtime.h>
#include <math.h>

using ushort_t = unsigned short;
using short8 = __attribute__((ext_vector_type(8))) short;
using floatx16 = __attribute__((ext_vector_type(16))) float;
using int4v = __attribute__((ext_vector_type(4))) int;
using int2v = __attribute__((ext_vector_type(2))) int;

constexpr int kB = 512, kT = 256, kH = 512, kHor = 64;
constexpr int NG = 4 * kH;  // 2048 packed gate rows
constexpr int HSP = 36;     // epilogue h-staging row pitch (ushorts)

__device__ __forceinline__ ushort_t f2bf(float v) {
  unsigned u = __builtin_bit_cast(unsigned, v);
  return (ushort_t)((u + 0x7FFFu + ((u >> 16) & 1u)) >> 16);
}
__device__ __forceinline__ float bf2f(ushort_t b) {
  unsigned u = (unsigned)b << 16;
  return __builtin_bit_cast(float, u);
}
__device__ __forceinline__ float sig_(float x) { return 1.0f / (1.0f + __expf(-x)); }

__device__ __forceinline__ void async16(const ushort_t* g, ushort_t* l) {
  __builtin_amdgcn_global_load_lds(
      (const __attribute__((address_space(1))) void*)g,
      (__attribute__((address_space(3))) void*)l, 16, 0, 0);
}

struct UnitP {
  const ushort_t *Whi, *Wlo;            // packed weights [r=j*4+g][k], stride Kw
  const ushort_t *B0hi, *B0lo;          // h source planes (B,H), k 0..511
  const ushort_t *B1hi, *B1lo;          // k 512..1023 (unit B)
  const float* bias;                    // packed [j*4+g]
  ushort_t *Hhi, *Hlo;                  // output h planes (B,H)
  int Kw;                               // 512 or 1024
};

struct EX {
  const float* xsrc; const float* wx; int xmode; int tcol;  // unit-A input term
  float* outp; int ocol;                // ocol>=0: out[:,ocol] = xsrc (LLC)
  float* inp_next; const float* headb; int do_init;
  const float* headW; float* head_acc; int do_head;
};

struct Ptrs {
  const float* x;
  const ushort_t *w0eh, *w0el, *w1eh, *w1el;
  const ushort_t *w0dh, *w0dl, *w1dh, *w1dl;
  ushort_t *h0h[2], *h0l[2], *h1h[2], *h1l[2];
  const float *be0, *be1, *bd0, *bd1, *wxe, *wxd;
  float *ib0, *ib1;
  const float *hW, *hb;
  float* out;
  unsigned *bar1, *barR, *barG;
};

// GEMM phase: BM=128 gate-rows x BN=64 batch, BK=64. 512 threads, 8 waves,
// each wave one 32x32 tile (wm = wv&3, wn = wv>>2).
// r15 post-mortem fixes vs r15: BK stays 64 (r14 barrier count), swizzle
// stays 8-slot q=row*8+(k8^(row&7)) (r14 bank behavior), B staged by 4 waves
// with r14's write-then-prefetch cadence. BN=64 kept -> weight bytes and
// 3 MB/XCD L2 footprint unchanged (r7/r10 failure mode avoided).
// Net effect vs r14: h sc-stream halves (96 -> 48 MB/phase); per-CU worst
// case (B-blocks: 512KB DMA + 256KB sc) equals r14's per-CU pair bytes.
// A (weights): global_load_lds DMA double-buffer. Waves 0..3: wave w stages
//   plane (w<2?hi:lo), rows (w&1)*64 + [0,64), 8 x 1KB issues, vmcnt(8).
// B (h planes): sc0 sc1 LLC-coherent reg staging, waves 4..7 (4,5: hi rows
//   0-31/32-63; 6,7: lo), 4 static dwordx4 each, vmcnt(0)-write + prefetch.
// LDS (ushorts): Abuf0 [0,16384) (hi 8192|lo 8192), Abuf1 [16384,32768),
//   Bbuf0 [32768,40960) (hi 4096|lo 4096), Bbuf1 [40960,49152). 96 KB.
// Global k-order and MFMA triple order identical to r14 -> bitwise-same acc.
__device__ __forceinline__ void run_unit(const UnitP& U, const EX& E, const bool isB,
                                         const int mb, const int nb,
                                         ushort_t* sm, ushort_t* hshi, ushort_t* hslo,
                                         float* creg) {
  const int tid = threadIdx.x;          // 0..511
  const int m0blk = mb * 128;
  const int n0blk = nb * 64;
  const int nkt = U.Kw >> 6;            // 8 or 16

  const int wv = tid >> 6;              // 0..7
  const int ln = tid & 63;
  const int l31 = ln & 31;
  const int half = ln >> 5;
  const int wm = wv & 3;                // m-tile 0..3
  const int wn = wv >> 2;               // n-tile 0..1
  const int m0w = wm * 32, n0w = wn * 32;

  const bool stA = wv < 4;

  const int r8 = ln >> 3;               // 0..7
  const int k8s = (ln & 7) ^ r8;        // source k8 for swizzled slot

  // ---- A staging (waves 0..3): plane (wv<2?hi:lo), rows (wv&1)*64.. ----
  const ushort_t* gsrcA = (wv < 2) ? U.Whi : U.Wlo;
  const int aRowBase = (wv & 1) * 64;
  const size_t aRowOff = (size_t)(m0blk + aRowBase + r8) * U.Kw + k8s * 8;
  const int aLds = ((wv < 2) ? 0 : 8192) + aRowBase * 64;

  auto issueA = [&](int kt, int bufsel) {
    ushort_t* lb = sm + bufsel * 16384 + aLds;
    const ushort_t* g0 = gsrcA + aRowOff + kt * 64;
    #pragma unroll
    for (int i = 0; i < 8; ++i)
      async16(g0 + (size_t)i * 8 * U.Kw, lb + i * 512);
  };

  // ---- B staging (waves 4..7): plane (wv<6?hi:lo), rows (wv&1)*32.. ----
  const ushort_t* b0p = (wv < 6) ? U.B0hi : U.B0lo;
  const ushort_t* b1p = (wv < 6) ? U.B1hi : U.B1lo;
  const int bRowBase = (wv & 1) * 32;
  const size_t bRowOff = (size_t)(n0blk + bRowBase + r8) * kH + k8s * 8;
  const int bLds = ((wv < 6) ? 0 : 4096) + bRowBase * 64;

  int4v q0, q1, q2, q3;
  auto issueB = [&](int ktc) {
    const ushort_t* bsrc = (ktc < 8) ? b0p : b1p;
    const int col0 = (ktc & 7) * 64;
    const ushort_t* g0 = bsrc + bRowOff + col0;
    asm volatile("global_load_dwordx4 %0, %1, off sc0 sc1"
                 : "=v"(q0) : "v"(g0) : "memory");
    asm volatile("global_load_dwordx4 %0, %1, off sc0 sc1"
                 : "=v"(q1) : "v"(g0 + (size_t)8 * kH) : "memory");
    asm volatile("global_load_dwordx4 %0, %1, off sc0 sc1"
                 : "=v"(q2) : "v"(g0 + (size_t)16 * kH) : "memory");
    asm volatile("global_load_dwordx4 %0, %1, off sc0 sc1"
                 : "=v"(q3) : "v"(g0 + (size_t)24 * kH) : "memory");
  };
  auto writeB = [&](int bufsel) {
    ushort_t* b = sm + 32768 + bufsel * 8192 + bLds;
    asm volatile("s_waitcnt vmcnt(0)" ::: "memory");   // q0..q3 materialized
    *(int4v*)(b + ln * 8) = q0;
    *(int4v*)(b + 512 + ln * 8) = q1;
    *(int4v*)(b + 1024 + ln * 8) = q2;
    *(int4v*)(b + 1536 + ln * 8) = q3;
    asm volatile("s_waitcnt lgkmcnt(0)" ::: "memory"); // regs reusable+visible
  };

  floatx16 acc;
  #pragma unroll
  for (int i = 0; i < 16; ++i) acc[i] = 0.0f;

  auto compute = [&](int bufsel) {
    const ushort_t* ba = sm + bufsel * 16384;
    const ushort_t* bb = sm + 32768 + bufsel * 8192;
    #pragma unroll
    for (int ks = 0; ks < 4; ++ks) {
      const int k8 = ks * 2 + half;
      const int ra = m0w + l31;
      const int rb = n0w + l31;
      const int qa = ra * 8 + (k8 ^ (ra & 7));
      const int qb = rb * 8 + (k8 ^ (rb & 7));
      short8 ahi = *(const short8*)(ba + qa * 8);
      short8 alo = *(const short8*)(ba + 8192 + qa * 8);
      short8 bhi = *(const short8*)(bb + qb * 8);
      short8 blo = *(const short8*)(bb + 4096 + qb * 8);
      acc = __builtin_amdgcn_mfma_f32_32x32x16_bf16(alo, bhi, acc, 0, 0, 0);
      acc = __builtin_amdgcn_mfma_f32_32x32x16_bf16(ahi, blo, acc, 0, 0, 0);
      acc = __builtin_amdgcn_mfma_f32_32x32x16_bf16(ahi, bhi, acc, 0, 0, 0);
    }
  };

  // ---- prologue ----
  if (stA) issueA(0, 0); else issueB(0);

  // ---- main loop: 2 barriers per k-step (r14 cadence) ----
  for (int kt = 0; kt < nkt; ++kt) {
    if (kt > 0) {                       // WAR: all done computing buf[(kt+1)&1]
      asm volatile("" ::: "memory");
      __builtin_amdgcn_s_barrier();
      asm volatile("" ::: "memory");
    }
    if (stA) {
      if (kt + 1 < nkt) {
        issueA(kt + 1, (kt + 1) & 1);
        asm volatile("s_waitcnt vmcnt(8)" ::: "memory");  // A(kt) landed
      } else {
        asm volatile("s_waitcnt vmcnt(0)" ::: "memory");
      }
    } else {
      writeB(kt & 1);                   // vmcnt(0) inside: B(kt) landed
      if (kt + 1 < nkt) issueB(kt + 1);
    }
    asm volatile("" ::: "memory");
    __builtin_amdgcn_s_barrier();       // buf[kt&1] fully staged & visible
    asm volatile("" ::: "memory");
    compute(kt & 1);
  }
  asm volatile("s_waitcnt vmcnt(0)" ::: "memory");      // nothing dangling

  // ---- epilogue: lane n = n0blk + n0w + l31; 4 j-groups x 4 gates ----
  const int jt0 = mb * 32;
  const int ng = n0blk + n0w + l31;
  float xv = 0.0f;
  if (!isB) {
    if (E.xmode == 0) xv = E.xsrc[(size_t)ng * kT + E.tcol];
    else xv = __hip_atomic_load((float*)&E.xsrc[ng], __ATOMIC_RELAXED,
                                __HIP_MEMORY_SCOPE_AGENT);
  }

  #pragma unroll
  for (int rg = 0; rg < 4; ++rg) {
    const int jl = wm * 8 + rg * 2 + half;      // j within block's 32
    const int jg = jt0 + jl;
    const float4 bi = *(const float4*)&U.bias[jg * 4];
    float gi = acc[rg * 4 + 0] + bi.x;
    float gf = acc[rg * 4 + 1] + bi.y;
    float gg = acc[rg * 4 + 2] + bi.z;
    float go = acc[rg * 4 + 3] + bi.w;
    if (!isB) {
      const float4 wx4 = *(const float4*)&E.wx[jg * 4];
      gi += xv * wx4.x; gf += xv * wx4.y; gg += xv * wx4.z; go += xv * wx4.w;
    }
    const float i_ = sig_(gi), f_ = sig_(gf), g_ = tanhf(gg), o_ = sig_(go);
    const float cn = f_ * creg[rg] + i_ * g_;   // c lives in registers
    creg[rg] = cn;
    const float hn = o_ * tanhf(cn);
    const ushort_t hhi = f2bf(hn);
    const ushort_t hlo = f2bf(hn - bf2f(hhi));
    const int nbk = n0w + l31;
    hshi[nbk * HSP + jl] = hhi;
    hslo[nbk * HSP + jl] = hlo;
  }
  __syncthreads();

  // coalesced h-plane write (B,H): 8 threads/row x 8B/plane, through to LLC
  {
    const int nr = tid >> 3;            // 0..63
    const int jq = (tid & 7) * 4;       // 0..28
    const unsigned a0 = hshi[nr * HSP + jq + 0], a1 = hshi[nr * HSP + jq + 1];
    const unsigned a2 = hshi[nr * HSP + jq + 2], a3 = hshi[nr * HSP + jq + 3];
    const unsigned b0 = hslo[nr * HSP + jq + 0], b1 = hslo[nr * HSP + jq + 1];
    const unsigned b2 = hslo[nr * HSP + jq + 2], b3 = hslo[nr * HSP + jq + 3];
    int2v vh, vl;
    vh[0] = (int)(a0 | (a1 << 16)); vh[1] = (int)(a2 | (a3 << 16));
    vl[0] = (int)(b0 | (b1 << 16)); vl[1] = (int)(b2 | (b3 << 16));
    ushort_t* ph = &U.Hhi[(size_t)(n0blk + nr) * kH + jt0 + jq];
    ushort_t* pl = &U.Hlo[(size_t)(n0blk + nr) * kH + jt0 + jq];
    asm volatile("global_store_dwordx2 %0, %1, off sc0 sc1"
                 :: "v"(ph), "v"(vh) : "memory");
    asm volatile("global_store_dwordx2 %0, %1, off sc0 sc1"
                 :: "v"(pl), "v"(vl) : "memory");
  }

  if (isB) {
    if (E.do_head && tid < 64) {
      float s = 0.0f;
      #pragma unroll
      for (int jb = 0; jb < 32; ++jb)
        s += (bf2f(hshi[tid * HSP + jb]) + bf2f(hslo[tid * HSP + jb])) * E.headW[jt0 + jb];
      atomicAdd(&E.head_acc[n0blk + tid], s);   // device scope -> LLC
    }
  } else if (mb == 0 && tid < 64) {
    const int n = n0blk + tid;
    if (E.do_init)
      __hip_atomic_store(&E.inp_next[n], E.headb[0], __ATOMIC_RELAXED,
                         __HIP_MEMORY_SCOPE_AGENT);
    if (E.ocol >= 0) {
      const float v = __hip_atomic_load((float*)&E.xsrc[n], __ATOMIC_RELAXED,
                                        __HIP_MEMORY_SCOPE_AGENT);
      E.outp[(size_t)n * kHor + E.ocol] = v;
    }
  }
}

// Persistent kernel: 256 blocks x 512 threads (A-team 0..127, B 128..255).
// 2-D XCD map: x = bid&7, kq = bid>>3 (0..15);
//   mb = (kq&3) + 4*(x&3)   (16 values, 4/XCD -> enc weights 3 MB, resident)
//   nb = (kq>>2) + 4*(x>>2) (8 values, 4/XCD -> minimal h import)
// Per-nb-group barriers (r14 win): group = 16 A + 16 B = 32 blocks; the
// dependency graph is closed within the group (h panel rows, ib, head, out).
__global__ __launch_bounds__(512, 2) void lstm_persist(Ptrs P) {
  __shared__ __align__(16) ushort_t sm[49152];   // A 2x32KB + B 2x16KB = 96KB
  __shared__ __align__(16) ushort_t hshi[64 * HSP];
  __shared__ __align__(16) ushort_t hslo[64 * HSP];

  const int tid = threadIdx.x;
  const int bx = blockIdx.x;
  const bool isB = bx >= 128;
  const int bid = isB ? bx - 128 : bx;
  const int xs = bid & 7;            // ~XCD id under round-robin dispatch
  const int kq = bid >> 3;           // 0..15
  const int mb = (kq & 3) + 4 * (xs & 3);      // 0..15
  const int nb = (kq >> 2) + 4 * (xs >> 2);    // 0..7
  const int grp = nb;                // barrier group: 32 blocks (16 A + 16 B)

  float creg[4] = {0.0f, 0.0f, 0.0f, 0.0f};  // block-private cell state

  int gen = 0;
  auto gbar = [&]() {
    asm volatile("s_waitcnt vmcnt(0)" ::: "memory");  // drain sc-stores
    __syncthreads();
    if (tid == 0) {
      unsigned old = __hip_atomic_fetch_add(&P.bar1[grp * 32], 1u,
                         __ATOMIC_RELAXED, __HIP_MEMORY_SCOPE_AGENT);
      if (old == (unsigned)(gen * 32 + 31))            // last of the 32
        __hip_atomic_store(&P.barG[grp * 32], (unsigned)(gen + 1),
                           __ATOMIC_RELAXED, __HIP_MEMORY_SCOPE_AGENT);
      while (__hip_atomic_load(&P.barG[grp * 32], __ATOMIC_RELAXED,
                               __HIP_MEMORY_SCOPE_AGENT) <= (unsigned)gen)
        __builtin_amdgcn_s_sleep(2);
    }
    __syncthreads();
    ++gen;
  };

  // ---------- encoder: wavefront phases p=0..256 (L0[p] || L1[p-1]) ----------
  for (int p = 0; p <= kT; ++p) {
    const int rd = p & 1, wr = (p + 1) & 1;
    const bool active = isB ? (p >= 1) : (p < kT);
    if (active) {
      UnitP U; EX E = {};
      if (!isB) {
        U = UnitP{P.w0eh, P.w0el, P.h0h[rd], P.h0l[rd], P.h0h[rd], P.h0l[rd],
                  P.be0, P.h0h[wr], P.h0l[wr], 512};
        E.xsrc = P.x; E.wx = P.wxe; E.xmode = 0; E.tcol = p; E.ocol = -1;
      } else {
        U = UnitP{P.w1eh, P.w1el, P.h0h[rd], P.h0l[rd], P.h1h[rd], P.h1l[rd],
                  P.be1, P.h1h[wr], P.h1l[wr], 1024};
        E.ocol = -1;
      }
      run_unit(U, E, isB, mb, nb, sm, hshi, hslo, creg);
    }
    gbar();
  }
  // h0 final in planes[0], h1 final in planes[1]

  // ---------- decoder: serial, 2 phases/step ----------
  for (int t = 0; t < kHor; ++t) {
    const int r0 = t & 1, w0i = (t + 1) & 1;
    const int r1 = (t + 1) & 1, w1i = t & 1;
    float* ibr = (t & 1) ? P.ib1 : P.ib0;
    float* ibw = (t & 1) ? P.ib0 : P.ib1;
    if (!isB) {
      UnitP U = {P.w0dh, P.w0dl, P.h0h[r0], P.h0l[r0], P.h0h[r0], P.h0l[r0],
                 P.bd0, P.h0h[w0i], P.h0l[w0i], 512};
      EX E = {};
      E.wx = P.wxd;
      if (t == 0) { E.xsrc = P.x; E.xmode = 0; E.tcol = 255; E.ocol = -1; }
      else        { E.xsrc = ibr; E.xmode = 1; E.ocol = t - 1; E.outp = P.out; }
      E.do_init = 1; E.inp_next = ibw; E.headb = P.hb;
      run_unit(U, E, false, mb, nb, sm, hshi, hslo, creg);
    }
    gbar();
    if (isB) {
      UnitP U = {P.w1dh, P.w1dl, P.h0h[w0i], P.h0l[w0i], P.h1h[r1], P.h1l[r1],
                 P.bd1, P.h1h[w1i], P.h1l[w1i], 1024};
      EX E = {};
      E.ocol = -1;
      E.do_head = 1; E.headW = P.hW; E.head_acc = ibw;
      run_unit(U, E, true, mb, nb, sm, hshi, hslo, creg);
    }
    gbar();
  }

  // last head output: out[:,63] = ib0 (post-gbar, group-fresh)
  if (!isB && mb == 0 && tid < 64) {
    const int n = nb * 64 + tid;
    P.out[(size_t)n * kHor + 63] =
        __hip_atomic_load(P.ib0 + n, __ATOMIC_RELAXED, __HIP_MEMORY_SCOPE_AGENT);
  }
}

// ---- prep kernels ----
__global__ void prep_w(const float* __restrict__ s0, const float* __restrict__ s1,
                       ushort_t* __restrict__ hi, ushort_t* __restrict__ lo, int Kw) {
  const int k = blockIdx.x * 256 + threadIdx.x;
  const int r = blockIdx.y;                 // packed row j*4+g
  const int j = r >> 2, g = r & 3;
  const int srow = g * kH + j;
  const float v = (k < kH) ? s0[(size_t)srow * kH + k]
                           : s1[(size_t)srow * kH + (k - kH)];
  const ushort_t h = f2bf(v);
  const ushort_t l = f2bf(v - bf2f(h));
  hi[(size_t)r * Kw + k] = h;
  lo[(size_t)r * Kw + k] = l;
}

__global__ void prep_vec(const float* __restrict__ src, float* __restrict__ dst) {
  const int t = blockIdx.x * 256 + threadIdx.x;   // 2048
  const int j = t >> 2, g = t & 3;
  dst[t] = src[g * kH + j];
}

__global__ void init_zero(ushort_t* p0, ushort_t* p1, ushort_t* p2, ushort_t* p3,
                          ushort_t* p4, ushort_t* p5, ushort_t* p6, ushort_t* p7) {
  const int i = blockIdx.x * 256 + threadIdx.x;   // 262144
  p0[i] = 0; p1[i] = 0; p2[i] = 0; p3[i] = 0;
  p4[i] = 0; p5[i] = 0; p6[i] = 0; p7[i] = 0;
}

__global__ void init_bar(unsigned* b) {
  const int i = blockIdx.x * 256 + threadIdx.x;
  if (i < 2112) b[i] = 0;
}

extern "C" void kernel_launch(void* const* d_in, const int* in_sizes, int n_in,
                              void* d_out, int out_size, void* d_ws, size_t ws_size,
                              hipStream_t stream) {
  const float* x     = (const float*)d_in[0];
  const float* eWih0 = (const float*)d_in[1];
  const float* eWhh0 = (const float*)d_in[2];
  const float* eb0   = (const float*)d_in[3];
  const float* eWih1 = (const float*)d_in[4];
  const float* eWhh1 = (const float*)d_in[5];
  const float* eb1   = (const float*)d_in[6];
  const float* dWih0 = (const float*)d_in[7];
  const float* dWhh0 = (const float*)d_in[8];
  const float* db0   = (const float*)d_in[9];
  const float* dWih1 = (const float*)d_in[10];
  const float* dWhh1 = (const float*)d_in[11];
  const float* db1   = (const float*)d_in[12];
  const float* hW    = (const float*)d_in[13];
  const float* hb    = (const float*)d_in[14];
  float* out = (float*)d_out;

  char* w = (char*)d_ws;
  size_t off = 0;
  auto aus = [&](size_t n) { ushort_t* p = (ushort_t*)(w + off); off += ((n * 2 + 255) & ~(size_t)255); return p; };
  auto afl = [&](size_t n) { float* p = (float*)(w + off); off += ((n * 4 + 255) & ~(size_t)255); return p; };

  ushort_t* w0e_hi = aus((size_t)NG * 512); ushort_t* w0e_lo = aus((size_t)NG * 512);
  ushort_t* w1e_hi = aus((size_t)NG * 1024); ushort_t* w1e_lo = aus((size_t)NG * 1024);
  ushort_t* w0d_hi = aus((size_t)NG * 512); ushort_t* w0d_lo = aus((size_t)NG * 512);
  ushort_t* w1d_hi = aus((size_t)NG * 1024); ushort_t* w1d_lo = aus((size_t)NG * 1024);
  ushort_t* h0hi[2] = {aus(kB * kH), aus(kB * kH)};
  ushort_t* h0lo[2] = {aus(kB * kH), aus(kB * kH)};
  ushort_t* h1hi[2] = {aus(kB * kH), aus(kB * kH)};
  ushort_t* h1lo[2] = {aus(kB * kH), aus(kB * kH)};
  float* be0 = afl(NG); float* be1 = afl(NG);
  float* bd0 = afl(NG); float* bd1 = afl(NG);
  float* wxe = afl(NG); float* wxd = afl(NG);
  float* ib0 = afl(kB); float* ib1 = afl(kB);
  unsigned* barb = (unsigned*)(w + off); off += ((2112 * 4 + 255) & ~(size_t)255);

  prep_w<<<dim3(2, NG), 256, 0, stream>>>(eWhh0, eWhh0, w0e_hi, w0e_lo, 512);
  prep_w<<<dim3(4, NG), 256, 0, stream>>>(eWih1, eWhh1, w1e_hi, w1e_lo, 1024);
  prep_w<<<dim3(2, NG), 256, 0, stream>>>(dWhh0, dWhh0, w0d_hi, w0d_lo, 512);
  prep_w<<<dim3(4, NG), 256, 0, stream>>>(dWih1, dWhh1, w1d_hi, w1d_lo, 1024);
  prep_vec<<<8, 256, 0, stream>>>(eb0, be0);
  prep_vec<<<8, 256, 0, stream>>>(eb1, be1);
  prep_vec<<<8, 256, 0, stream>>>(db0, bd0);
  prep_vec<<<8, 256, 0, stream>>>(db1, bd1);
  prep_vec<<<8, 256, 0, stream>>>(eWih0, wxe);
  prep_vec<<<8, 256, 0, stream>>>(dWih0, wxd);
  init_zero<<<1024, 256, 0, stream>>>(h0hi[0], h0hi[1], h0lo[0], h0lo[1],
                                      h1hi[0], h1hi[1], h1lo[0], h1lo[1]);
  init_bar<<<9, 256, 0, stream>>>(barb);

  Ptrs P = {};
  P.x = x;
  P.w0eh = w0e_hi; P.w0el = w0e_lo; P.w1eh = w1e_hi; P.w1el = w1e_lo;
  P.w0dh = w0d_hi; P.w0dl = w0d_lo; P.w1dh = w1d_hi; P.w1dl = w1d_lo;
  P.h0h[0] = h0hi[0]; P.h0h[1] = h0hi[1];
  P.h0l[0] = h0lo[0]; P.h0l[1] = h0lo[1];
  P.h1h[0] = h1hi[0]; P.h1h[1] = h1hi[1];
  P.h1l[0] = h1lo[0]; P.h1l[1] = h1lo[1];
  P.be0 = be0; P.be1 = be1; P.bd0 = bd0; P.bd1 = bd1;
  P.wxe = wxe; P.wxd = wxd;
  P.ib0 = ib0; P.ib1 = ib1;
  P.hW = hW; P.hb = hb;
  P.out = out;
  P.bar1 = barb; P.barR = barb + 2048; P.barG = barb + 1024;

  lstm_persist<<<256, 512, 0, stream>>>(P);
}

// Round 17
// 5717.522 us; speedup vs baseline: 1.5988x; 1.5197x over previous
//
#include <hip/hip_runtime.h>
#include <math.h>

using ushort_t = unsigned short;
using short8 = __attribute__((ext_vector_type(8))) short;
using floatx16 = __attribute__((ext_vector_type(16))) float;
using int4v = __attribute__((ext_vector_type(4))) int;
using int2v = __attribute__((ext_vector_type(2))) int;

constexpr int kB = 512, kT = 256, kH = 512, kHor = 64;
constexpr int NG = 4 * kH;  // 2048 packed gate rows

__device__ __forceinline__ ushort_t f2bf(float v) {
  unsigned u = __builtin_bit_cast(unsigned, v);
  return (ushort_t)((u + 0x7FFFu + ((u >> 16) & 1u)) >> 16);
}
__device__ __forceinline__ float bf2f(ushort_t b) {
  unsigned u = (unsigned)b << 16;
  return __builtin_bit_cast(float, u);
}
__device__ __forceinline__ float sig_(float x) { return 1.0f / (1.0f + __expf(-x)); }

__device__ __forceinline__ void async16(const ushort_t* g, ushort_t* l) {
  __builtin_amdgcn_global_load_lds(
      (const __attribute__((address_space(1))) void*)g,
      (__attribute__((address_space(3))) void*)l, 16, 0, 0);
}

struct UnitP {
  const ushort_t *Whi, *Wlo;            // packed weights [r=j*4+g][k], stride Kw
  const ushort_t *B0hi, *B0lo;          // h source planes (B,H), k 0..511
  const ushort_t *B1hi, *B1lo;          // k 512..1023 (unit B)
  const float* bias;                    // packed [j*4+g]
  ushort_t *Hhi, *Hlo;                  // output h planes (B,H)
  int Kw;                               // 512 or 1024
};

struct EX {
  const float* xsrc; const float* wx; int xmode; int tcol;  // unit-A input term
  float* outp; int ocol;                // ocol>=0: out[:,ocol] = xsrc (LLC)
  float* inp_next; const float* headb; int do_init;
  const float* headW; float* head_acc; int do_head;
};

struct Ptrs {
  const float* x;
  const ushort_t *w0eh, *w0el, *w1eh, *w1el;
  const ushort_t *w0dh, *w0dl, *w1dh, *w1dl;
  ushort_t *h0h[2], *h0l[2], *h1h[2], *h1l[2];
  const float *be0, *be1, *bd0, *bd1, *wxe, *wxd;
  float *ib0, *ib1;
  const float *hW, *hb;
  float* out;
  unsigned *bar1, *barR, *barG;
};

// One GEMM phase: 64 gate-rows x 64 batch, 4 waves of one 32x32 mfma tile.
// (Round-14 champion kernel, restored byte-identical: 5726 us verified.)
// Weights: plain cached global_load_lds DMA -> L2-resident (never fenced).
// h planes: sc0 sc1 write-through stores + sc0 sc1 reads, coherent at LLC.
// Phase time == 96 MB sc h-stream @ ~5.6 TB/s MALL; 2 blocks/CU hide stalls.
// All byte-reduction alternatives measured worse (r7/r9/r10/r11/r12/r15/r16).
__device__ __forceinline__ void run_unit(const UnitP& U, const EX& E, const bool isB,
                                         const int mb, const int nb,
                                         ushort_t* sm, ushort_t* hshi, ushort_t* hslo,
                                         float* creg) {
  const int tid = threadIdx.x;
  const int m0blk = mb * 64;
  const int n0blk = nb * 64;
  const int nkt = U.Kw >> 6;

  const int wv = tid >> 6;
  const int ln = tid & 63;
  const int l31 = ln & 31;
  const int half = ln >> 5;
  const int wm = wv & 1, wn = wv >> 1;
  const int m0w = wm * 32, n0w = wn * 32;

  // staging invariants (wave 0/1: weight planes hi/lo via DMA;
  //                     wave 2/3: h planes hi/lo via sc-coherent reg staging)
  const int r8 = ln >> 3;
  const int k8s = (ln & 7) ^ r8;
  const bool stA = wv < 2;
  const ushort_t* gsrcA = (wv == 0) ? U.Whi : U.Wlo;
  const ushort_t* b0p = (wv == 2) ? U.B0hi : U.B0lo;
  const ushort_t* b1p = (wv == 2) ? U.B1hi : U.B1lo;
  ushort_t* lwb = &sm[wv * 4096];

  int4v breg[8];

  auto issueW = [&](int kt, int bufsel) {
    ushort_t* lb = lwb + bufsel * 16384;
    const ushort_t* g0 = gsrcA + (size_t)(m0blk + r8) * U.Kw + kt * 64 + k8s * 8;
    #pragma unroll
    for (int i = 0; i < 8; ++i)
      async16(g0 + (size_t)i * 8 * U.Kw, lb + i * 512);
  };
  auto issueB = [&](int kt) {
    const ushort_t* bsrc = (kt < 8) ? b0p : b1p;
    const int col0 = (kt & 7) * 64;
    const ushort_t* g0 = bsrc + (size_t)(n0blk + r8) * kH + col0 + k8s * 8;
    #pragma unroll
    for (int i = 0; i < 8; ++i)
      asm volatile("global_load_dwordx4 %0, %1, off sc0 sc1"
                   : "=v"(breg[i])
                   : "v"(g0 + (size_t)i * 8 * kH)
                   : "memory");
  };
  auto writeB = [&](int bufsel) {
    ushort_t* lb = lwb + bufsel * 16384;
    asm volatile("s_waitcnt vmcnt(0)" ::: "memory");   // breg materialized
    #pragma unroll
    for (int i = 0; i < 8; ++i)
      *(int4v*)(lb + i * 512 + ln * 8) = breg[i];
    asm volatile("s_waitcnt lgkmcnt(0)" ::: "memory"); // breg reusable + visible
  };

  floatx16 acc;
  #pragma unroll
  for (int i = 0; i < 16; ++i) acc[i] = 0.0f;

  if (stA) issueW(0, 0); else issueB(0);

  for (int kt = 0; kt < nkt; ++kt) {
    const int cur = kt & 1;
    if (kt + 1 < nkt) {
      if (kt > 0) {           // WAR: everyone done computing buf[cur^1]
        asm volatile("" ::: "memory");
        __builtin_amdgcn_s_barrier();
        asm volatile("" ::: "memory");
      }
      if (stA) {
        issueW(kt + 1, cur ^ 1);
        asm volatile("" ::: "memory");
        __builtin_amdgcn_s_waitcnt(0xF78);  // vmcnt(8): my cur-tile DMA done
      } else {
        writeB(cur);          // land kt's h data into buf[cur]
        issueB(kt + 1);       // prefetch next tile from LLC
      }
    } else {
      if (stA) {
        asm volatile("" ::: "memory");
        __builtin_amdgcn_s_waitcnt(0xF70);  // vmcnt(0)
      } else {
        writeB(cur);
      }
    }
    asm volatile("" ::: "memory");
    __builtin_amdgcn_s_barrier();          // all waves' cur data visible
    asm volatile("" ::: "memory");

    const ushort_t* base = &sm[cur * 16384];
    #pragma unroll
    for (int ks = 0; ks < 4; ++ks) {
      const int k8 = ks * 2 + half;
      const int qa = (m0w + l31) * 8 + (k8 ^ (l31 & 7));
      const int qb = (n0w + l31) * 8 + (k8 ^ (l31 & 7));
      short8 ahi = *(const short8*)(base + qa * 8);
      short8 alo = *(const short8*)(base + 4096 + qa * 8);
      short8 bhi = *(const short8*)(base + 8192 + qb * 8);
      short8 blo = *(const short8*)(base + 12288 + qb * 8);
      acc = __builtin_amdgcn_mfma_f32_32x32x16_bf16(alo, bhi, acc, 0, 0, 0);
      acc = __builtin_amdgcn_mfma_f32_32x32x16_bf16(ahi, blo, acc, 0, 0, 0);
      acc = __builtin_amdgcn_mfma_f32_32x32x16_bf16(ahi, bhi, acc, 0, 0, 0);
    }
  }

  // ---- epilogue: lane holds 4 j-groups x 4 gates for one n ----
  const int jt0 = mb * 16;
  const int ng = n0blk + n0w + l31;
  float xv = 0.0f;
  if (!isB) {
    if (E.xmode == 0) xv = E.xsrc[(size_t)ng * kT + E.tcol];
    else xv = __hip_atomic_load((float*)&E.xsrc[ng], __ATOMIC_RELAXED,
                                __HIP_MEMORY_SCOPE_AGENT);
  }

  #pragma unroll
  for (int rg = 0; rg < 4; ++rg) {
    const int jl = wm * 8 + rg * 2 + half;      // j within block's 16
    const int jg = jt0 + jl;
    const float4 bi = *(const float4*)&U.bias[jg * 4];
    float gi = acc[rg * 4 + 0] + bi.x;
    float gf = acc[rg * 4 + 1] + bi.y;
    float gg = acc[rg * 4 + 2] + bi.z;
    float go = acc[rg * 4 + 3] + bi.w;
    if (!isB) {
      const float4 wx4 = *(const float4*)&E.wx[jg * 4];
      gi += xv * wx4.x; gf += xv * wx4.y; gg += xv * wx4.z; go += xv * wx4.w;
    }
    const float i_ = sig_(gi), f_ = sig_(gf), g_ = tanhf(gg), o_ = sig_(go);
    const float cn = f_ * creg[rg] + i_ * g_;   // c lives in registers
    creg[rg] = cn;
    const float hn = o_ * tanhf(cn);
    const ushort_t hhi = f2bf(hn);
    const ushort_t hlo = f2bf(hn - bf2f(hhi));
    const int nbk = n0w + l31;
    hshi[nbk * 18 + jl] = hhi;
    hslo[nbk * 18 + jl] = hlo;
  }
  __syncthreads();

  // coalesced h-plane write (B,H): 4 threads/row x 8B, write-through to LLC
  {
    const int nbk = tid >> 2;
    const int jq = (tid & 3) * 4;
    const unsigned a0 = hshi[nbk * 18 + jq + 0], a1 = hshi[nbk * 18 + jq + 1];
    const unsigned a2 = hshi[nbk * 18 + jq + 2], a3 = hshi[nbk * 18 + jq + 3];
    const unsigned b0 = hslo[nbk * 18 + jq + 0], b1 = hslo[nbk * 18 + jq + 1];
    const unsigned b2 = hslo[nbk * 18 + jq + 2], b3 = hslo[nbk * 18 + jq + 3];
    int2v vh, vl;
    vh[0] = (int)(a0 | (a1 << 16)); vh[1] = (int)(a2 | (a3 << 16));
    vl[0] = (int)(b0 | (b1 << 16)); vl[1] = (int)(b2 | (b3 << 16));
    ushort_t* ph = &U.Hhi[(size_t)(n0blk + nbk) * kH + jt0 + jq];
    ushort_t* pl = &U.Hlo[(size_t)(n0blk + nbk) * kH + jt0 + jq];
    asm volatile("global_store_dwordx2 %0, %1, off sc0 sc1"
                 :: "v"(ph), "v"(vh) : "memory");
    asm volatile("global_store_dwordx2 %0, %1, off sc0 sc1"
                 :: "v"(pl), "v"(vl) : "memory");
  }

  if (isB) {
    if (E.do_head && tid < 64) {
      float s = 0.0f;
      #pragma unroll
      for (int jb = 0; jb < 16; ++jb)
        s += (bf2f(hshi[tid * 18 + jb]) + bf2f(hslo[tid * 18 + jb])) * E.headW[jt0 + jb];
      atomicAdd(&E.head_acc[n0blk + tid], s);   // device scope -> LLC
    }
  } else if (mb == 0 && tid < 64) {
    const int n = n0blk + tid;
    if (E.do_init)
      __hip_atomic_store(&E.inp_next[n], E.headb[0], __ATOMIC_RELAXED,
                         __HIP_MEMORY_SCOPE_AGENT);
    if (E.ocol >= 0) {
      const float v = __hip_atomic_load((float*)&E.xsrc[n], __ATOMIC_RELAXED,
                                        __HIP_MEMORY_SCOPE_AGENT);
      E.outp[(size_t)n * kHor + E.ocol] = v;
    }
  }
}

// Persistent kernel: 512 blocks (A-team 0..255, B-team 256..511).
// 2-D XCD mapping:
//   x = bid&7 (~XCD under round-robin), kq = bid>>3,
//   mb = (kq&7) + 8*(x&3)  -> 8 mb-slices per XCD (enc weights 3 MB, resident)
//   nb = (kq>>3) + 4*(x>>2) -> 4 nb panels per XCD (minimal h import)
// Per-nb-group barriers: group = 32 A + 32 B = 64 blocks; the dependency
// graph is closed within the group (h panel rows, ib, head partials, out).
__global__ __launch_bounds__(256, 2) void lstm_persist(Ptrs P) {
  __shared__ __align__(16) ushort_t sm[32768];   // 2 buffers x 4 planes x 4096
  __shared__ ushort_t hshi[64 * 18];
  __shared__ ushort_t hslo[64 * 18];

  const int tid = threadIdx.x;
  const int bx = blockIdx.x;
  const bool isB = bx >= 256;
  const int bid = isB ? bx - 256 : bx;
  const int xs = bid & 7;            // ~XCD id under round-robin dispatch
  const int kq = bid >> 3;           // 0..31
  const int mb = (kq & 7) + 8 * (xs & 3);
  const int nb = (kq >> 3) + 4 * (xs >> 2);
  const int grp = nb;                // barrier group: 64 blocks (32 A + 32 B)

  float creg[4] = {0.0f, 0.0f, 0.0f, 0.0f};  // block-private cell state

  int gen = 0;
  auto gbar = [&]() {
    asm volatile("s_waitcnt vmcnt(0)" ::: "memory");  // drain sc-stores
    __syncthreads();
    if (tid == 0) {
      unsigned old = __hip_atomic_fetch_add(&P.bar1[grp * 32], 1u,
                         __ATOMIC_RELAXED, __HIP_MEMORY_SCOPE_AGENT);
      if (old == (unsigned)(gen * 64 + 63))            // last of the 64
        __hip_atomic_store(&P.barG[grp * 32], (unsigned)(gen + 1),
                           __ATOMIC_RELAXED, __HIP_MEMORY_SCOPE_AGENT);
      while (__hip_atomic_load(&P.barG[grp * 32], __ATOMIC_RELAXED,
                               __HIP_MEMORY_SCOPE_AGENT) <= (unsigned)gen)
        __builtin_amdgcn_s_sleep(2);
    }
    __syncthreads();
    ++gen;
  };

  // ---------- encoder: wavefront phases p=0..256 (L0[p] || L1[p-1]) ----------
  for (int p = 0; p <= kT; ++p) {
    const int rd = p & 1, wr = (p + 1) & 1;
    const bool active = isB ? (p >= 1) : (p < kT);
    if (active) {
      UnitP U; EX E = {};
      if (!isB) {
        U = UnitP{P.w0eh, P.w0el, P.h0h[rd], P.h0l[rd], P.h0h[rd], P.h0l[rd],
                  P.be0, P.h0h[wr], P.h0l[wr], 512};
        E.xsrc = P.x; E.wx = P.wxe; E.xmode = 0; E.tcol = p; E.ocol = -1;
      } else {
        U = UnitP{P.w1eh, P.w1el, P.h0h[rd], P.h0l[rd], P.h1h[rd], P.h1l[rd],
                  P.be1, P.h1h[wr], P.h1l[wr], 1024};
        E.ocol = -1;
      }
      run_unit(U, E, isB, mb, nb, sm, hshi, hslo, creg);
    }
    gbar();
  }
  // h0 final in planes[0], h1 final in planes[1]

  // ---------- decoder: serial, 2 phases/step ----------
  for (int t = 0; t < kHor; ++t) {
    const int r0 = t & 1, w0i = (t + 1) & 1;
    const int r1 = (t + 1) & 1, w1i = t & 1;
    float* ibr = (t & 1) ? P.ib1 : P.ib0;
    float* ibw = (t & 1) ? P.ib0 : P.ib1;
    if (!isB) {
      UnitP U = {P.w0dh, P.w0dl, P.h0h[r0], P.h0l[r0], P.h0h[r0], P.h0l[r0],
                 P.bd0, P.h0h[w0i], P.h0l[w0i], 512};
      EX E = {};
      E.wx = P.wxd;
      if (t == 0) { E.xsrc = P.x; E.xmode = 0; E.tcol = 255; E.ocol = -1; }
      else        { E.xsrc = ibr; E.xmode = 1; E.ocol = t - 1; E.outp = P.out; }
      E.do_init = 1; E.inp_next = ibw; E.headb = P.hb;
      run_unit(U, E, false, mb, nb, sm, hshi, hslo, creg);
    }
    gbar();
    if (isB) {
      UnitP U = {P.w1dh, P.w1dl, P.h0h[w0i], P.h0l[w0i], P.h1h[r1], P.h1l[r1],
                 P.bd1, P.h1h[w1i], P.h1l[w1i], 1024};
      EX E = {};
      E.ocol = -1;
      E.do_head = 1; E.headW = P.hW; E.head_acc = ibw;
      run_unit(U, E, true, mb, nb, sm, hshi, hslo, creg);
    }
    gbar();
  }

  // last head output: out[:,63] = ib[(63+1)&1] = ib0 (post-gbar, group-fresh)
  if (!isB && mb == 0 && tid < 64) {
    const int n = nb * 64 + tid;
    P.out[(size_t)n * kHor + 63] =
        __hip_atomic_load(P.ib0 + n, __ATOMIC_RELAXED, __HIP_MEMORY_SCOPE_AGENT);
  }
}

// ---- prep kernels ----
__global__ void prep_w(const float* __restrict__ s0, const float* __restrict__ s1,
                       ushort_t* __restrict__ hi, ushort_t* __restrict__ lo, int Kw) {
  const int k = blockIdx.x * 256 + threadIdx.x;
  const int r = blockIdx.y;                 // packed row j*4+g
  const int j = r >> 2, g = r & 3;
  const int srow = g * kH + j;
  const float v = (k < kH) ? s0[(size_t)srow * kH + k]
                           : s1[(size_t)srow * kH + (k - kH)];
  const ushort_t h = f2bf(v);
  const ushort_t l = f2bf(v - bf2f(h));
  hi[(size_t)r * Kw + k] = h;
  lo[(size_t)r * Kw + k] = l;
}

__global__ void prep_vec(const float* __restrict__ src, float* __restrict__ dst) {
  const int t = blockIdx.x * 256 + threadIdx.x;   // 2048
  const int j = t >> 2, g = t & 3;
  dst[t] = src[g * kH + j];
}

__global__ void init_zero(ushort_t* p0, ushort_t* p1, ushort_t* p2, ushort_t* p3,
                          ushort_t* p4, ushort_t* p5, ushort_t* p6, ushort_t* p7) {
  const int i = blockIdx.x * 256 + threadIdx.x;   // 262144
  p0[i] = 0; p1[i] = 0; p2[i] = 0; p3[i] = 0;
  p4[i] = 0; p5[i] = 0; p6[i] = 0; p7[i] = 0;
}

__global__ void init_bar(unsigned* b) {
  const int i = blockIdx.x * 256 + threadIdx.x;
  if (i < 2112) b[i] = 0;
}

extern "C" void kernel_launch(void* const* d_in, const int* in_sizes, int n_in,
                              void* d_out, int out_size, void* d_ws, size_t ws_size,
                              hipStream_t stream) {
  const float* x     = (const float*)d_in[0];
  const float* eWih0 = (const float*)d_in[1];
  const float* eWhh0 = (const float*)d_in[2];
  const float* eb0   = (const float*)d_in[3];
  const float* eWih1 = (const float*)d_in[4];
  const float* eWhh1 = (const float*)d_in[5];
  const float* eb1   = (const float*)d_in[6];
  const float* dWih0 = (const float*)d_in[7];
  const float* dWhh0 = (const float*)d_in[8];
  const float* db0   = (const float*)d_in[9];
  const float* dWih1 = (const float*)d_in[10];
  const float* dWhh1 = (const float*)d_in[11];
  const float* db1   = (const float*)d_in[12];
  const float* hW    = (const float*)d_in[13];
  const float* hb    = (const float*)d_in[14];
  float* out = (float*)d_out;

  char* w = (char*)d_ws;
  size_t off = 0;
  auto aus = [&](size_t n) { ushort_t* p = (ushort_t*)(w + off); off += ((n * 2 + 255) & ~(size_t)255); return p; };
  auto afl = [&](size_t n) { float* p = (float*)(w + off); off += ((n * 4 + 255) & ~(size_t)255); return p; };

  ushort_t* w0e_hi = aus((size_t)NG * 512); ushort_t* w0e_lo = aus((size_t)NG * 512);
  ushort_t* w1e_hi = aus((size_t)NG * 1024); ushort_t* w1e_lo = aus((size_t)NG * 1024);
  ushort_t* w0d_hi = aus((size_t)NG * 512); ushort_t* w0d_lo = aus((size_t)NG * 512);
  ushort_t* w1d_hi = aus((size_t)NG * 1024); ushort_t* w1d_lo = aus((size_t)NG * 1024);
  ushort_t* h0hi[2] = {aus(kB * kH), aus(kB * kH)};
  ushort_t* h0lo[2] = {aus(kB * kH), aus(kB * kH)};
  ushort_t* h1hi[2] = {aus(kB * kH), aus(kB * kH)};
  ushort_t* h1lo[2] = {aus(kB * kH), aus(kB * kH)};
  float* be0 = afl(NG); float* be1 = afl(NG);
  float* bd0 = afl(NG); float* bd1 = afl(NG);
  float* wxe = afl(NG); float* wxd = afl(NG);
  float* ib0 = afl(kB); float* ib1 = afl(kB);
  unsigned* barb = (unsigned*)(w + off); off += ((2112 * 4 + 255) & ~(size_t)255);

  prep_w<<<dim3(2, NG), 256, 0, stream>>>(eWhh0, eWhh0, w0e_hi, w0e_lo, 512);
  prep_w<<<dim3(4, NG), 256, 0, stream>>>(eWih1, eWhh1, w1e_hi, w1e_lo, 1024);
  prep_w<<<dim3(2, NG), 256, 0, stream>>>(dWhh0, dWhh0, w0d_hi, w0d_lo, 512);
  prep_w<<<dim3(4, NG), 256, 0, stream>>>(dWih1, dWhh1, w1d_hi, w1d_lo, 1024);
  prep_vec<<<8, 256, 0, stream>>>(eb0, be0);
  prep_vec<<<8, 256, 0, stream>>>(eb1, be1);
  prep_vec<<<8, 256, 0, stream>>>(db0, bd0);
  prep_vec<<<8, 256, 0, stream>>>(db1, bd1);
  prep_vec<<<8, 256, 0, stream>>>(eWih0, wxe);
  prep_vec<<<8, 256, 0, stream>>>(dWih0, wxd);
  init_zero<<<1024, 256, 0, stream>>>(h0hi[0], h0hi[1], h0lo[0], h0lo[1],
                                      h1hi[0], h1hi[1], h1lo[0], h1lo[1]);
  init_bar<<<9, 256, 0, stream>>>(barb);

  Ptrs P = {};
  P.x = x;
  P.w0eh = w0e_hi; P.w0el = w0e_lo; P.w1eh = w1e_hi; P.w1el = w1e_lo;
  P.w0dh = w0d_hi; P.w0dl = w0d_lo; P.w1dh = w1d_hi; P.w1dl = w1d_lo;
  P.h0h[0] = h0hi[0]; P.h0h[1] = h0hi[1];
  P.h0l[0] = h0lo[0]; P.h0l[1] = h0lo[1];
  P.h1h[0] = h1hi[0]; P.h1h[1] = h1hi[1];
  P.h1l[0] = h1lo[0]; P.h1l[1] = h1lo[1];
  P.be0 = be0; P.be1 = be1; P.bd0 = bd0; P.bd1 = bd1;
  P.wxe = wxe; P.wxd = wxd;
  P.ib0 = ib0; P.ib1 = ib1;
  P.hW = hW; P.hb = hb;
  P.out = out;
  P.bar1 = barb; P.barR = barb + 2048; P.barG = barb + 1024;

  lstm_persist<<<512, 256, 0, stream>>>(P);
}